// Round 1
// baseline (799.325 us; speedup 1.0000x reference)
//
#include <hip/hip_runtime.h>
#include <hip/hip_fp16.h>

// RGCN 3-layer, transform-first formulation:
//   out[n] = sum_e inv[dst,type] * (x[src] @ W_type)  + x[n]@Wroot + bias
// Edges counting-sorted by (dst*8+type) once -> atomic-free segment accumulate.
// GEMMs in fp16 MFMA (fp32 accumulate). Layer 3 computed only at root rows.

typedef _Float16 f16;
typedef _Float16 f16x8 __attribute__((ext_vector_type(8)));
typedef _Float16 f16x4 __attribute__((ext_vector_type(4)));
typedef float f32x4 __attribute__((ext_vector_type(4)));

#define NREL 8

// ---------------- setup kernels ----------------
__global__ void k_count(const int* __restrict__ dst, const int* __restrict__ et,
                        int E, int* __restrict__ cnt) {
  int e = blockIdx.x * 256 + threadIdx.x;
  if (e < E) atomicAdd(&cnt[dst[e] * NREL + et[e]], 1);
}

__global__ void k_inv(const int* __restrict__ cnt, float* __restrict__ inv, int n) {
  int i = blockIdx.x * 256 + threadIdx.x;
  if (i < n) { int c = cnt[i]; inv[i] = 1.0f / (float)(c > 1 ? c : 1); }
}

// exclusive scan pass 1: blocks of 4096 (256 thr x 16), write block-local excl + partial
__global__ void k_scan1(const int* __restrict__ in, int* __restrict__ out,
                        int* __restrict__ part, int n) {
  __shared__ int sh[256];
  int b = blockIdx.x, t = threadIdx.x;
  int base = b * 4096 + t * 16;
  int v[16]; int s = 0;
#pragma unroll
  for (int j = 0; j < 16; j++) { int idx = base + j; int x = (idx < n) ? in[idx] : 0; v[j] = s; s += x; }
  sh[t] = s; __syncthreads();
  for (int off = 1; off < 256; off <<= 1) {
    int x = 0; if (t >= off) x = sh[t - off];
    __syncthreads();
    if (t >= off) sh[t] += x;
    __syncthreads();
  }
  int excl = (t == 0) ? 0 : sh[t - 1];
  if (t == 255) part[b] = sh[255];
#pragma unroll
  for (int j = 0; j < 16; j++) { int idx = base + j; if (idx < n) out[idx] = v[j] + excl; }
}

__global__ void k_scan2(int* __restrict__ part, int nb) {  // nb <= 256, 1 block
  __shared__ int sh[256];
  int t = threadIdx.x;
  sh[t] = (t < nb) ? part[t] : 0; __syncthreads();
  for (int off = 1; off < 256; off <<= 1) {
    int x = 0; if (t >= off) x = sh[t - off];
    __syncthreads();
    if (t >= off) sh[t] += x;
    __syncthreads();
  }
  if (t < nb) part[t] = (t == 0) ? 0 : sh[t - 1];
}

__global__ void k_scan3(int* __restrict__ out, const int* __restrict__ part, int n) {
  int i = blockIdx.x * 256 + threadIdx.x;
  if (i < n) out[i] += part[i >> 12];
}

__global__ void k_sentinel(int* __restrict__ p, int v) { *p = v; }

__global__ void k_scatter(const int* __restrict__ src, const int* __restrict__ dstv,
                          const int* __restrict__ et, int E,
                          const int* __restrict__ off2, int* __restrict__ fill,
                          int* __restrict__ sps) {
  int e = blockIdx.x * 256 + threadIdx.x;
  if (e >= E) return;
  int key = dstv[e] * NREL + et[e];
  int pos = off2[key] + atomicAdd(&fill[key], 1);
  sps[pos] = src[e] | (et[e] << 20);   // src < 2^20, type in bits 20..22
}

__global__ void k_f32_to_f16(const float* __restrict__ in, f16* __restrict__ out, int n4) {
  int i = blockIdx.x * 256 + threadIdx.x;
  if (i < n4) {
    float4 v = ((const float4*)in)[i];
    f16x4 o; o[0] = (f16)v.x; o[1] = (f16)v.y; o[2] = (f16)v.z; o[3] = (f16)v.w;
    ((f16x4*)out)[i] = o;
  }
}

// transpose weight chunk(s): src[(rlo+c)][k][h] (fp32) -> dst[(c*128+h)][k] (f16)
__global__ void k_tpw(const float* __restrict__ src, f16* __restrict__ dst, int rlo) {
  int h = blockIdx.x, c = blockIdx.y, k = threadIdx.x;
  dst[(size_t)(c * 128 + h) * 128 + k] = (f16)src[(size_t)(rlo + c) * 16384 + k * 128 + h];
}

// ---------------- GEMM: C[M x (gridDim.y*128)] = A[M x 128] * Bt^T, Bt is [cols][128] ----------------
template <typename OUT_T>
__global__ __launch_bounds__(256) void k_gemm(const f16* __restrict__ A,
                                              const f16* __restrict__ Bt,
                                              OUT_T* __restrict__ C, int M, int ldc) {
  __shared__ f16 As[128 * 136];
  __shared__ f16 Bs[128 * 136];
  int m0 = blockIdx.x * 128, n0 = blockIdx.y * 128;
  int tid = threadIdx.x;
#pragma unroll
  for (int cch = 0; cch < 8; cch++) {
    int ci = tid + cch * 256;       // 0..2047, 8 f16 each
    int row = ci >> 4, c8 = ci & 15;
    f16x8 va = {};
    int gm = m0 + row;
    if (gm < M) va = *(const f16x8*)(A + (size_t)gm * 128 + c8 * 8);
    *(f16x8*)(As + row * 136 + c8 * 8) = va;
    *(f16x8*)(Bs + row * 136 + c8 * 8) = *(const f16x8*)(Bt + (size_t)(n0 + row) * 128 + c8 * 8);
  }
  __syncthreads();
  int wid = tid >> 6, lane = tid & 63;
  int wm = (wid & 1) * 64, wn = (wid >> 1) * 64;
  int lm = lane & 15, lk = lane >> 4;
  f32x4 acc[4][4] = {};
#pragma unroll
  for (int ks = 0; ks < 4; ks++) {
    int k0 = ks * 32;
    f16x8 a[4], b[4];
#pragma unroll
    for (int i = 0; i < 4; i++) {
      a[i] = *(const f16x8*)(As + (wm + i * 16 + lm) * 136 + k0 + lk * 8);
      b[i] = *(const f16x8*)(Bs + (wn + i * 16 + lm) * 136 + k0 + lk * 8);
    }
#pragma unroll
    for (int i = 0; i < 4; i++)
#pragma unroll
      for (int j = 0; j < 4; j++)
        acc[i][j] = __builtin_amdgcn_mfma_f32_16x16x32_f16(a[i], b[j], acc[i][j], 0, 0, 0);
  }
#pragma unroll
  for (int i = 0; i < 4; i++)
#pragma unroll
    for (int j = 0; j < 4; j++)
#pragma unroll
      for (int q = 0; q < 4; q++) {
        int gm = m0 + wm + i * 16 + lk * 4 + q;
        int gn = n0 + wn + j * 16 + lm;
        if (gm < M) C[(size_t)gm * ldc + gn] = (OUT_T)acc[i][j][q];
      }
}

// ---------------- edge aggregation (one block per node, 128 threads) ----------------
__global__ __launch_bounds__(128) void k_edge(const f16* __restrict__ Y,
                                              const int* __restrict__ sps,
                                              const int* __restrict__ off2,
                                              const float* __restrict__ inv,
                                              float* __restrict__ acc,
                                              const float* __restrict__ bias,
                                              f16* __restrict__ hout,
                                              int rlo, int rcount, int last) {
  int n = blockIdx.x, t = threadIdx.x;
  int e0 = off2[n * NREL + rlo];
  int e1 = off2[n * NREL + rlo + rcount];
  float a = acc[(size_t)n * 128 + t];
  float a2 = 0.f;
  int e = e0;
  for (; e + 1 < e1; e += 2) {
    int ps0 = sps[e], ps1 = sps[e + 1];
    int s0 = ps0 & 0xFFFFF, ty0 = ps0 >> 20;
    int s1 = ps1 & 0xFFFFF, ty1 = ps1 >> 20;
    float v0 = (float)Y[((size_t)s0 * rcount + (ty0 - rlo)) * 128 + t];
    float v1 = (float)Y[((size_t)s1 * rcount + (ty1 - rlo)) * 128 + t];
    a += v0 * inv[n * NREL + ty0];
    a2 += v1 * inv[n * NREL + ty1];
  }
  if (e < e1) {
    int ps = sps[e];
    int s = ps & 0xFFFFF, ty = ps >> 20;
    a += (float)Y[((size_t)s * rcount + (ty - rlo)) * 128 + t] * inv[n * NREL + ty];
  }
  a += a2;
  if (last) {
    a += bias[t];
    a = fmaxf(a, 0.0f);
    hout[(size_t)n * 128 + t] = (f16)a;
  } else {
    acc[(size_t)n * 128 + t] = a;
  }
}

// ---------------- layer 3: only at root rows, weights in LDS ----------------
__global__ __launch_bounds__(128) void k_layer3(const f16* __restrict__ h2,
                                                const int* __restrict__ sps,
                                                const int* __restrict__ off2,
                                                const float* __restrict__ inv,
                                                const int* __restrict__ ridx,
                                                const float* __restrict__ wrel,
                                                const float* __restrict__ wroot,
                                                const float* __restrict__ b3,
                                                float* __restrict__ out) {
  __shared__ f16 W[9 * 128 * 16];   // chunks 0..7 = wrel3[r][k][c], chunk 8 = root3[k][c]
  __shared__ float red[2][16];
  int t = threadIdx.x;
  for (int j = t; j < 9 * 2048; j += 128)
    W[j] = (f16)((j < 8 * 2048) ? wrel[j] : wroot[j - 8 * 2048]);
  __syncthreads();
  int i = blockIdx.x;
  int n = ridx[i];
  int c = t & 15, kg = t >> 4;   // 8 k-groups of 16
  float a = 0.f;
  int e0 = off2[n * NREL], e1 = off2[n * NREL + NREL];
  for (int e = e0; e < e1; e++) {
    int ps = sps[e];
    int s = ps & 0xFFFFF, ty = ps >> 20;
    float sc = inv[n * NREL + ty];
    float p = 0.f;
#pragma unroll
    for (int j = 0; j < 16; j++) {
      int k = kg * 16 + j;
      p += (float)h2[(size_t)s * 128 + k] * (float)W[ty * 2048 + k * 16 + c];
    }
    a += sc * p;
  }
  {
    float p = 0.f;
#pragma unroll
    for (int j = 0; j < 16; j++) {
      int k = kg * 16 + j;
      p += (float)h2[(size_t)n * 128 + k] * (float)W[8 * 2048 + k * 16 + c];
    }
    a += p;
  }
  a += __shfl_xor(a, 16);
  a += __shfl_xor(a, 32);
  if ((t & 63) < 16) red[t >> 6][t & 15] = a;
  __syncthreads();
  if (t < 16) out[(size_t)i * 16 + t] = red[0][t] + red[1][t] + b3[t];
}

// ---------------- host ----------------
extern "C" void kernel_launch(void* const* d_in, const int* in_sizes, int n_in,
                              void* d_out, int out_size, void* d_ws, size_t ws_size,
                              hipStream_t stream) {
  const float* x     = (const float*)d_in[0];
  const int*   eidx  = (const int*)d_in[1];
  const int*   etyp  = (const int*)d_in[2];
  const int*   ridx  = (const int*)d_in[3];
  const float* wrel1 = (const float*)d_in[4];
  const float* root1 = (const float*)d_in[5];
  const float* b1    = (const float*)d_in[6];
  const float* wrel2 = (const float*)d_in[7];
  const float* root2 = (const float*)d_in[8];
  const float* b2    = (const float*)d_in[9];
  const float* wrel3 = (const float*)d_in[10];
  const float* root3 = (const float*)d_in[11];
  const float* b3    = (const float*)d_in[12];

  int N = in_sizes[0] / 128;
  int E = in_sizes[2];
  int NROOT = in_sizes[3];
  const int* esrc = eidx;
  const int* edst = eidx + E;
  int NRk = N * NREL;

  // workspace layout (256B aligned chunks)
  char* p = (char*)d_ws;
  auto alloc = [&](size_t bytes) { void* r = (void*)p; p += (bytes + 255) & ~(size_t)255; return r; };
  int*   cnt    = (int*)alloc((size_t)NRk * 4);
  int*   off2   = (int*)alloc((size_t)(NRk + 1) * 4);
  int*   fill   = (int*)alloc((size_t)NRk * 4);
  float* inv    = (float*)alloc((size_t)NRk * 4);
  int*   part   = (int*)alloc(4096 * 4);
  int*   sps    = (int*)alloc((size_t)E * 4);
  f16*   Xh     = (f16*)alloc((size_t)N * 128 * 2);   // also reused as h2
  f16*   h1     = (f16*)alloc((size_t)N * 128 * 2);
  float* acc    = (float*)alloc((size_t)N * 128 * 4);
  f16*   Wt     = (f16*)alloc((size_t)NREL * 128 * 128 * 2);
  f16*   Wrt    = (f16*)alloc((size_t)128 * 128 * 2);
  f16*   h2     = Xh;  // alias: Xh dead after layer-1 GEMMs

  size_t used = (size_t)(p - (char*)d_ws);
  size_t remain = ws_size > used ? ws_size - used : 0;
  int rcount = NREL;
  while (rcount > 1 && (size_t)N * 128 * 2 * rcount > remain) rcount >>= 1;
  f16* Y = (f16*)alloc((size_t)N * 128 * 2 * rcount);

  int eb = (E + 255) / 256;
  hipMemsetAsync(cnt, 0, (size_t)NRk * 4, stream);
  hipMemsetAsync(fill, 0, (size_t)NRk * 4, stream);
  k_count<<<eb, 256, 0, stream>>>(edst, etyp, E, cnt);
  k_inv<<<(NRk + 255) / 256, 256, 0, stream>>>(cnt, inv, NRk);
  int nb1 = (NRk + 4095) / 4096;   // 196 for N=100K
  k_scan1<<<nb1, 256, 0, stream>>>(cnt, off2, part, NRk);
  k_scan2<<<1, 256, 0, stream>>>(part, nb1);
  k_scan3<<<(NRk + 255) / 256, 256, 0, stream>>>(off2, part, NRk);
  k_sentinel<<<1, 1, 0, stream>>>(off2 + NRk, E);
  k_scatter<<<eb, 256, 0, stream>>>(esrc, edst, etyp, E, off2, fill, sps);
  k_f32_to_f16<<<((N * 32) + 255) / 256, 256, 0, stream>>>(x, Xh, N * 32);

  int mb = (N + 127) / 128;
  auto layer = [&](const f16* Ain, const float* wrel, const float* wroot,
                   const float* bias, f16* hout) {
    k_tpw<<<dim3(128, 1), 128, 0, stream>>>(wroot, Wrt, 0);
    k_gemm<float><<<dim3(mb, 1), 256, 0, stream>>>(Ain, Wrt, acc, N, 128);
    int ng = NREL / rcount;
    for (int g = 0; g < ng; g++) {
      int rlo = g * rcount;
      k_tpw<<<dim3(128, rcount), 128, 0, stream>>>(wrel, Wt, rlo);
      k_gemm<f16><<<dim3(mb, rcount), 256, 0, stream>>>(Ain, Wt, Y, N, rcount * 128);
      k_edge<<<N, 128, 0, stream>>>(Y, sps, off2, inv, acc, bias, hout,
                                    rlo, rcount, (g == ng - 1) ? 1 : 0);
    }
  };

  layer(Xh, wrel1, root1, b1, h1);
  layer(h1, wrel2, root2, b2, h2);
  k_layer3<<<NROOT, 128, 0, stream>>>(h2, sps, off2, inv, ridx, wrel3, root3, b3,
                                      (float*)d_out);
}

// Round 2
// 794.017 us; speedup vs baseline: 1.0067x; 1.0067x over previous
//
#include <hip/hip_runtime.h>
#include <hip/hip_fp16.h>

// RGCN 3-layer, transform-first:
//   h[n] = relu( Y[n,root] + sum_e inv[dst,type] * Y[src,type] + bias ),
//   Y = X @ [W_0..W_7, W_root]   (9 column blocks of 128, fp16 MFMA)
// Edges counting-sorted by dst only; per-(node,type) mean counts computed
// on the fly per segment. Layer-2 restricted to nodes layer-3 actually reads.

typedef _Float16 f16;
typedef _Float16 f16x8 __attribute__((ext_vector_type(8)));
typedef _Float16 f16x4 __attribute__((ext_vector_type(4)));
typedef float f32x4 __attribute__((ext_vector_type(4)));

#define NREL 8

// ---------------- setup kernels ----------------
__global__ void k_hist(const int* __restrict__ dst, int E, int* __restrict__ cnt) {
  int e = blockIdx.x * 256 + threadIdx.x;
  if (e < E) atomicAdd(&cnt[dst[e]], 1);
}

// exclusive scan pass 1: blocks of 4096 (256 thr x 16)
__global__ void k_scan1(const int* __restrict__ in, int* __restrict__ out,
                        int* __restrict__ part, int n) {
  __shared__ int sh[256];
  int b = blockIdx.x, t = threadIdx.x;
  int base = b * 4096 + t * 16;
  int v[16]; int s = 0;
#pragma unroll
  for (int j = 0; j < 16; j++) { int idx = base + j; int x = (idx < n) ? in[idx] : 0; v[j] = s; s += x; }
  sh[t] = s; __syncthreads();
  for (int off = 1; off < 256; off <<= 1) {
    int x = 0; if (t >= off) x = sh[t - off];
    __syncthreads();
    if (t >= off) sh[t] += x;
    __syncthreads();
  }
  int excl = (t == 0) ? 0 : sh[t - 1];
  if (t == 255) part[b] = sh[255];
#pragma unroll
  for (int j = 0; j < 16; j++) { int idx = base + j; if (idx < n) out[idx] = v[j] + excl; }
}

__global__ void k_scan2(int* __restrict__ part, int nb) {  // nb <= 256, 1 block
  __shared__ int sh[256];
  int t = threadIdx.x;
  sh[t] = (t < nb) ? part[t] : 0; __syncthreads();
  for (int off = 1; off < 256; off <<= 1) {
    int x = 0; if (t >= off) x = sh[t - off];
    __syncthreads();
    if (t >= off) sh[t] += x;
    __syncthreads();
  }
  if (t < nb) part[t] = (t == 0) ? 0 : sh[t - 1];
}

__global__ void k_scan3(int* __restrict__ out, const int* __restrict__ part, int n) {
  int i = blockIdx.x * 256 + threadIdx.x;
  if (i < n) out[i] += part[i >> 12];
}

__global__ void k_sentinel(int* __restrict__ p, int v) { *p = v; }

__global__ void k_scatter(const int* __restrict__ src, const int* __restrict__ dstv,
                          const int* __restrict__ et, int E,
                          const int* __restrict__ off, int* __restrict__ fill,
                          int* __restrict__ sps) {
  int e = blockIdx.x * 256 + threadIdx.x;
  if (e >= E) return;
  int key = dstv[e];
  int pos = off[key] + atomicAdd(&fill[key], 1);
  sps[pos] = src[e] | (et[e] << 20);   // src < 2^20, type in bits 20..22
}

__global__ void k_f32_to_f16(const float* __restrict__ in, f16* __restrict__ out, int n4) {
  int i = blockIdx.x * 256 + threadIdx.x;
  if (i < n4) {
    float4 v = ((const float4*)in)[i];
    f16x4 o; o[0] = (f16)v.x; o[1] = (f16)v.y; o[2] = (f16)v.z; o[3] = (f16)v.w;
    ((f16x4*)out)[i] = o;
  }
}

// mark nodes whose h2 is read by layer 3: roots + src of root in-edges
__global__ void k_mark(const int* __restrict__ ridx, const int* __restrict__ off,
                       const int* __restrict__ sps, int* __restrict__ mark) {
  int i = blockIdx.x, t = threadIdx.x;
  int n = ridx[i];
  if (t == 0) mark[n] = 1;
  int e0 = off[n], e1 = off[n + 1];
  for (int e = e0 + t; e < e1; e += 64) mark[sps[e] & 0xFFFFF] = 1;
}

// transpose 9 weight chunks: 0..7 from wrel[r][k][h], 8 from wroot[k][h] -> Wt[(c*128+h)][k] f16
__global__ void k_tpw9(const float* __restrict__ wrel, const float* __restrict__ wroot,
                       f16* __restrict__ dst) {
  int h = blockIdx.x, c = blockIdx.y, k = threadIdx.x;
  float v = (c < 8) ? wrel[(size_t)c * 16384 + k * 128 + h] : wroot[k * 128 + h];
  dst[(size_t)(c * 128 + h) * 128 + k] = (f16)v;
}

// transpose chunk(s) for grouped fallback: src[(rlo+c)][k][h] -> dst[(c*128+h)][k]
__global__ void k_tpw(const float* __restrict__ src, f16* __restrict__ dst, int rlo) {
  int h = blockIdx.x, c = blockIdx.y, k = threadIdx.x;
  dst[(size_t)(c * 128 + h) * 128 + k] = (f16)src[(size_t)(rlo + c) * 16384 + k * 128 + h];
}

__global__ void k_tpw_root(const float* __restrict__ src, f16* __restrict__ dst) {
  int h = blockIdx.x, k = threadIdx.x;
  dst[(size_t)h * 128 + k] = (f16)src[(size_t)k * 128 + h];
}

// ---------------- GEMM: C[M x (gridDim.y*128)] = A[M x 128] * Bt^T, Bt is [cols][128] ----------------
template <typename OUT_T>
__global__ __launch_bounds__(256) void k_gemm(const f16* __restrict__ A,
                                              const f16* __restrict__ Bt,
                                              OUT_T* __restrict__ C, int M, int ldc) {
  __shared__ f16 As[128 * 136];
  __shared__ f16 Bs[128 * 136];
  int m0 = blockIdx.x * 128, n0 = blockIdx.y * 128;
  int tid = threadIdx.x;
#pragma unroll
  for (int cch = 0; cch < 8; cch++) {
    int ci = tid + cch * 256;       // 0..2047, 8 f16 each
    int row = ci >> 4, c8 = ci & 15;
    f16x8 va = {};
    int gm = m0 + row;
    if (gm < M) va = *(const f16x8*)(A + (size_t)gm * 128 + c8 * 8);
    *(f16x8*)(As + row * 136 + c8 * 8) = va;
    *(f16x8*)(Bs + row * 136 + c8 * 8) = *(const f16x8*)(Bt + (size_t)(n0 + row) * 128 + c8 * 8);
  }
  __syncthreads();
  int wid = tid >> 6, lane = tid & 63;
  int wm = (wid & 1) * 64, wn = (wid >> 1) * 64;
  int lm = lane & 15, lk = lane >> 4;
  f32x4 acc[4][4] = {};
#pragma unroll
  for (int ks = 0; ks < 4; ks++) {
    int k0 = ks * 32;
    f16x8 a[4], b[4];
#pragma unroll
    for (int i = 0; i < 4; i++) {
      a[i] = *(const f16x8*)(As + (wm + i * 16 + lm) * 136 + k0 + lk * 8);
      b[i] = *(const f16x8*)(Bs + (wn + i * 16 + lm) * 136 + k0 + lk * 8);
    }
#pragma unroll
    for (int i = 0; i < 4; i++)
#pragma unroll
      for (int j = 0; j < 4; j++)
        acc[i][j] = __builtin_amdgcn_mfma_f32_16x16x32_f16(a[i], b[j], acc[i][j], 0, 0, 0);
  }
#pragma unroll
  for (int i = 0; i < 4; i++)
#pragma unroll
    for (int j = 0; j < 4; j++)
#pragma unroll
      for (int q = 0; q < 4; q++) {
        int gm = m0 + wm + i * 16 + lk * 4 + q;
        int gn = n0 + wn + j * 16 + lm;
        if (gm < M) C[(size_t)gm * ldc + gn] = (OUT_T)acc[i][j][q];
      }
}

// ---------------- fused edge aggregation, 9-column Y (plan A) ----------------
__global__ __launch_bounds__(128) void k_edge9(const f16* __restrict__ Y,
                                               const int* __restrict__ sps,
                                               const int* __restrict__ off,
                                               const float* __restrict__ bias,
                                               f16* __restrict__ hout,
                                               const int* __restrict__ mark) {
  int n = blockIdx.x;
  if (mark && !mark[n]) return;
  int t = threadIdx.x;
  __shared__ int c8[8];
  __shared__ float sinv[8];
  if (t < 8) c8[t] = 0;
  __syncthreads();
  int e0 = off[n], e1 = off[n + 1];
  for (int e = e0 + t; e < e1; e += 128) atomicAdd(&c8[((unsigned)sps[e]) >> 20], 1);
  __syncthreads();
  if (t < 8) sinv[t] = 1.0f / (float)(c8[t] > 1 ? c8[t] : 1);
  __syncthreads();
  float a = (float)Y[((size_t)n * 9 + 8) * 128 + t] + bias[t];
  float a2 = 0.f;
  int e = e0;
  for (; e + 1 < e1; e += 2) {
    int ps0 = sps[e], ps1 = sps[e + 1];
    int s0 = ps0 & 0xFFFFF, ty0 = ((unsigned)ps0) >> 20;
    int s1 = ps1 & 0xFFFFF, ty1 = ((unsigned)ps1) >> 20;
    a  += (float)Y[((size_t)s0 * 9 + ty0) * 128 + t] * sinv[ty0];
    a2 += (float)Y[((size_t)s1 * 9 + ty1) * 128 + t] * sinv[ty1];
  }
  if (e < e1) {
    int ps = sps[e];
    int s = ps & 0xFFFFF, ty = ((unsigned)ps) >> 20;
    a += (float)Y[((size_t)s * 9 + ty) * 128 + t] * sinv[ty];
  }
  a = fmaxf(a + a2, 0.0f);
  hout[(size_t)n * 128 + t] = (f16)a;
}

// ---------------- grouped fallback edge aggregation (plan B) ----------------
__global__ __launch_bounds__(128) void k_edge_grp(const f16* __restrict__ Y,
                                                  const int* __restrict__ sps,
                                                  const int* __restrict__ off,
                                                  float* __restrict__ acc,
                                                  const float* __restrict__ bias,
                                                  f16* __restrict__ hout,
                                                  const int* __restrict__ mark,
                                                  int rlo, int rcount, int last) {
  int n = blockIdx.x;
  if (mark && !mark[n]) return;
  int t = threadIdx.x;
  __shared__ int c8[8];
  __shared__ float sinv[8];
  if (t < 8) c8[t] = 0;
  __syncthreads();
  int e0 = off[n], e1 = off[n + 1];
  for (int e = e0 + t; e < e1; e += 128) atomicAdd(&c8[((unsigned)sps[e]) >> 20], 1);
  __syncthreads();
  if (t < 8) sinv[t] = 1.0f / (float)(c8[t] > 1 ? c8[t] : 1);
  __syncthreads();
  float a = acc[(size_t)n * 128 + t];
  for (int e = e0; e < e1; e++) {
    int ps = sps[e];
    int s = ps & 0xFFFFF, ty = ((unsigned)ps) >> 20;
    if (ty >= rlo && ty < rlo + rcount)
      a += (float)Y[((size_t)s * rcount + (ty - rlo)) * 128 + t] * sinv[ty];
  }
  if (last) {
    a += bias[t];
    a = fmaxf(a, 0.0f);
    hout[(size_t)n * 128 + t] = (f16)a;
  } else {
    acc[(size_t)n * 128 + t] = a;
  }
}

// ---------------- layer 3: only at root rows, weights in LDS ----------------
__global__ __launch_bounds__(128) void k_layer3(const f16* __restrict__ h2,
                                                const int* __restrict__ sps,
                                                const int* __restrict__ off,
                                                const int* __restrict__ ridx,
                                                const float* __restrict__ wrel,
                                                const float* __restrict__ wroot,
                                                const float* __restrict__ b3,
                                                float* __restrict__ out) {
  __shared__ f16 W[9 * 128 * 16];   // chunks 0..7 = wrel3[r][k][c], chunk 8 = root3[k][c]
  __shared__ float red[2][16];
  __shared__ int c8[8];
  __shared__ float sinv[8];
  int t = threadIdx.x;
  int i = blockIdx.x;
  int n = ridx[i];
  int e0 = off[n], e1 = off[n + 1];
  if (t < 8) c8[t] = 0;
  for (int j = t; j < 9 * 2048; j += 128)
    W[j] = (f16)((j < 8 * 2048) ? wrel[j] : wroot[j - 8 * 2048]);
  __syncthreads();
  for (int e = e0 + t; e < e1; e += 128) atomicAdd(&c8[((unsigned)sps[e]) >> 20], 1);
  __syncthreads();
  if (t < 8) sinv[t] = 1.0f / (float)(c8[t] > 1 ? c8[t] : 1);
  __syncthreads();
  int c = t & 15, kg = t >> 4;   // 8 k-groups of 16
  float a = 0.f;
  for (int e = e0; e < e1; e++) {
    int ps = sps[e];
    int s = ps & 0xFFFFF, ty = ((unsigned)ps) >> 20;
    float p = 0.f;
#pragma unroll
    for (int j = 0; j < 16; j++) {
      int k = kg * 16 + j;
      p += (float)h2[(size_t)s * 128 + k] * (float)W[ty * 2048 + k * 16 + c];
    }
    a += sinv[ty] * p;
  }
  {
    float p = 0.f;
#pragma unroll
    for (int j = 0; j < 16; j++) {
      int k = kg * 16 + j;
      p += (float)h2[(size_t)n * 128 + k] * (float)W[8 * 2048 + k * 16 + c];
    }
    a += p;
  }
  a += __shfl_xor(a, 16);
  a += __shfl_xor(a, 32);
  if ((t & 63) < 16) red[t >> 6][t & 15] = a;
  __syncthreads();
  if (t < 16) out[(size_t)i * 16 + t] = red[0][t] + red[1][t] + b3[t];
}

// ---------------- host ----------------
extern "C" void kernel_launch(void* const* d_in, const int* in_sizes, int n_in,
                              void* d_out, int out_size, void* d_ws, size_t ws_size,
                              hipStream_t stream) {
  const float* x     = (const float*)d_in[0];
  const int*   eidx  = (const int*)d_in[1];
  const int*   etyp  = (const int*)d_in[2];
  const int*   ridx  = (const int*)d_in[3];
  const float* wrel1 = (const float*)d_in[4];
  const float* root1 = (const float*)d_in[5];
  const float* b1    = (const float*)d_in[6];
  const float* wrel2 = (const float*)d_in[7];
  const float* root2 = (const float*)d_in[8];
  const float* b2    = (const float*)d_in[9];
  const float* wrel3 = (const float*)d_in[10];
  const float* root3 = (const float*)d_in[11];
  const float* b3    = (const float*)d_in[12];

  int N = in_sizes[0] / 128;
  int E = in_sizes[2];
  int NROOT = in_sizes[3];
  const int* esrc = eidx;
  const int* edst = eidx + E;

  // workspace layout (256B aligned chunks)
  char* p = (char*)d_ws;
  auto alloc = [&](size_t bytes) { void* r = (void*)p; p += (bytes + 255) & ~(size_t)255; return r; };
  int*   cnt  = (int*)alloc((size_t)N * 4);
  int*   off  = (int*)alloc((size_t)(N + 1) * 4);
  int*   fill = (int*)alloc((size_t)N * 4);
  int*   mark = (int*)alloc((size_t)N * 4);
  int*   part = (int*)alloc(4096 * 4);
  int*   sps  = (int*)alloc((size_t)E * 4);
  f16*   Xh   = (f16*)alloc((size_t)N * 128 * 2);   // reused as h2
  f16*   h1   = (f16*)alloc((size_t)N * 128 * 2);
  f16*   Wt   = (f16*)alloc((size_t)9 * 128 * 128 * 2);
  f16*   h2   = Xh;  // alias: Xh dead after layer-1 GEMM

  size_t used = (size_t)(p - (char*)d_ws);
  size_t remain = ws_size > used ? ws_size - used : 0;
  size_t y9bytes = (size_t)N * 9 * 128 * 2;
  int planA = (remain >= y9bytes + 256) ? 1 : 0;

  int eb = (E + 255) / 256;
  hipMemsetAsync(cnt, 0, (size_t)N * 4, stream);
  hipMemsetAsync(fill, 0, (size_t)N * 4, stream);
  hipMemsetAsync(mark, 0, (size_t)N * 4, stream);
  k_hist<<<eb, 256, 0, stream>>>(edst, E, cnt);
  int nb1 = (N + 4095) / 4096;
  k_scan1<<<nb1, 256, 0, stream>>>(cnt, off, part, N);
  k_scan2<<<1, 256, 0, stream>>>(part, nb1);
  k_scan3<<<(N + 255) / 256, 256, 0, stream>>>(off, part, N);
  k_sentinel<<<1, 1, 0, stream>>>(off + N, E);
  k_scatter<<<eb, 256, 0, stream>>>(esrc, edst, etyp, E, off, fill, sps);
  k_mark<<<NROOT, 64, 0, stream>>>(ridx, off, sps, mark);
  k_f32_to_f16<<<((N * 32) + 255) / 256, 256, 0, stream>>>(x, Xh, N * 32);

  int mb = (N + 127) / 128;

  if (planA) {
    f16* Y = (f16*)alloc(y9bytes);
    auto layer = [&](const f16* Ain, const float* wrel, const float* wroot,
                     const float* bias, f16* hout, const int* mk) {
      k_tpw9<<<dim3(128, 9), 128, 0, stream>>>(wrel, wroot, Wt);
      k_gemm<f16><<<dim3(mb, 9), 256, 0, stream>>>(Ain, Wt, Y, N, 9 * 128);
      k_edge9<<<N, 128, 0, stream>>>(Y, sps, off, bias, hout, mk);
    };
    layer(Xh, wrel1, root1, b1, h1, nullptr);
    layer(h1, wrel2, root2, b2, h2, mark);
  } else {
    float* acc = (float*)alloc((size_t)N * 128 * 4);
    f16*   Wrt = (f16*)alloc((size_t)128 * 128 * 2);
    used = (size_t)(p - (char*)d_ws);
    remain = ws_size > used ? ws_size - used : 0;
    int rcount = NREL;
    while (rcount > 1 && (size_t)N * 128 * 2 * rcount > remain) rcount >>= 1;
    f16* Y = (f16*)alloc((size_t)N * 128 * 2 * rcount);
    int ng = NREL / rcount;
    auto layer = [&](const f16* Ain, const float* wrel, const float* wroot,
                     const float* bias, f16* hout, const int* mk) {
      k_tpw_root<<<128, 128, 0, stream>>>(wroot, Wrt);
      k_gemm<float><<<dim3(mb, 1), 256, 0, stream>>>(Ain, Wrt, acc, N, 128);
      for (int g = 0; g < ng; g++) {
        int rlo = g * rcount;
        k_tpw<<<dim3(128, rcount), 128, 0, stream>>>(wrel, Wt, rlo);
        k_gemm<f16><<<dim3(mb, rcount), 256, 0, stream>>>(Ain, Wt, Y, N, rcount * 128);
        k_edge_grp<<<N, 128, 0, stream>>>(Y, sps, off, acc, bias, hout, mk,
                                          rlo, rcount, (g == ng - 1) ? 1 : 0);
      }
    };
    layer(Xh, wrel1, root1, b1, h1, nullptr);
    layer(h1, wrel2, root2, b2, h2, mark);
  }

  k_layer3<<<NROOT, 128, 0, stream>>>(h2, sps, off, ridx, wrel3, root3, b3,
                                      (float*)d_out);
}